// Round 4
// baseline (176.716 us; speedup 1.0000x reference)
//
#include <hip/hip_runtime.h>
#include <cstdint>
#include <cstddef>

#define AUDIO_DIM 512
#define TEXT_DIM  768
#define HIDDEN    512
#define BATCH     8
#define ALEN      2048
#define TLEN      512

typedef _Float16 half8 __attribute__((ext_vector_type(8)));
typedef _Float16 half4_t __attribute__((ext_vector_type(4)));
typedef float floatx4 __attribute__((ext_vector_type(4)));

#define AS1 __attribute__((address_space(1)))
#define AS3 __attribute__((address_space(3)))

// Async global->LDS, 16B per lane. LDS dest = wave-uniform base + lane*16.
__device__ __forceinline__ void gload_lds16(const void* g, void* l) {
    __builtin_amdgcn_global_load_lds((const AS1 void*)g, (AS3 void*)l, 16, 0, 0);
}

// XOR swizzle: 16B chunk c of row r lives at slot c ^ swz(r); makes the
// 64B-row fragment reads 2-way bank aliasing (free) instead of 8-way.
__device__ __forceinline__ int swz(int r) { return (r >> 1) & 3; }

// Counted vmcnt waits (T4, m135-verified semantics: wait until outstanding<=N).
// "memory" clobber pins all memory ops (incl. global_load_lds intrinsics and
// ds_read) on their side of the wait.
#define VMCNT(N) asm volatile("s_waitcnt vmcnt(" #N ")" ::: "memory")
// Fence before overwriting an LDS region this wave just ds_read from:
// lgkmcnt(0) ensures reads completed into VGPRs; sched_barrier stops the
// compiler hoisting the following stage above it (rule #18 analog).
#define LDS_REUSE_FENCE()                                   \
    do {                                                    \
        asm volatile("s_waitcnt lgkmcnt(0)" ::: "memory");  \
        __builtin_amdgcn_sched_barrier(0);                  \
    } while (0)

// ---------------------------------------------------------------------------
// prep: ONE kernel for all input conditioning.
//   blocks [0,8192)      : audio fp32 -> f16 (float4-vectorized)
//   blocks [8192,11264)  : text  fp32 -> f16
//   blocks [11264,11520) : Wq [512][512] -> Wq_t [512][512] f16 (transpose)
//   blocks [11520,11904) : Wk [768][512] -> Wk_t [512][768] f16
//   blocks [11904,12288) : Wv [768][512] -> Wv_t [512][768] f16
// ---------------------------------------------------------------------------
__global__ __launch_bounds__(256) void prep(
    const float* __restrict__ audio, const float* __restrict__ text,
    const float* __restrict__ Wq, const float* __restrict__ Wk,
    const float* __restrict__ Wv,
    _Float16* __restrict__ audio_h, _Float16* __restrict__ text_h,
    _Float16* __restrict__ Wq_t, _Float16* __restrict__ Wk_t,
    _Float16* __restrict__ Wv_t)
{
    __shared__ _Float16 tt[32 * 33];
    const int bid = blockIdx.x, tid = threadIdx.x;
    if (bid < 11264) {
        const float* src; _Float16* dst; int i;
        if (bid < 8192) { src = audio; dst = audio_h; i = bid * 256 + tid; }
        else            { src = text;  dst = text_h;  i = (bid - 8192) * 256 + tid; }
        float4 v = ((const float4*)src)[i];
        half4_t h;
        h.x = (_Float16)v.x; h.y = (_Float16)v.y; h.z = (_Float16)v.z; h.w = (_Float16)v.w;
        ((half4_t*)dst)[i] = h;
    } else {
        const float* src; _Float16* dst; int R, lb;
        if (bid < 11520)      { lb = bid - 11264; src = Wq; dst = Wq_t; R = 512; }
        else if (bid < 11904) { lb = bid - 11520; src = Wk; dst = Wk_t; R = 768; }
        else                  { lb = bid - 11904; src = Wv; dst = Wv_t; R = 768; }
        const int C = 512;
        const int c0 = (lb & 15) * 32, r0 = (lb >> 4) * 32;
        const int tx = tid & 31, ty = tid >> 5;   // 32 x 8
#pragma unroll
        for (int i = 0; i < 4; i++) {
            int r = ty + i * 8;
            tt[r * 33 + tx] = (_Float16)src[(size_t)(r0 + r) * C + c0 + tx];
        }
        __syncthreads();
#pragma unroll
        for (int i = 0; i < 4; i++) {
            int r = ty + i * 8;
            dst[(size_t)(c0 + r) * R + r0 + tx] = tt[tx * 33 + r];
        }
    }
}

// ---------------------------------------------------------------------------
// Shared f16 MFMA GEMM body: C[.,N] tile at (m0,n0) = A[M,K] @ Bt[N,K]^T.
// 128x128 tile, BK=32, 256 threads / 4 waves, wave = 64x64 via 4x4 MFMA
// tiles of 16x16x32. OUT16: f16 out + bias; ROWBIAS: bias indexed by row.
// ---------------------------------------------------------------------------
template <bool OUT16, bool ROWBIAS>
__device__ __forceinline__ void gemm_body(
    const _Float16* __restrict__ A, const _Float16* __restrict__ Bt,
    const float* __restrict__ bias, void* __restrict__ Cp,
    int N, int K, int m0, int n0, _Float16* Asm, _Float16* Bsm)
{
    const int tid = threadIdx.x;
    const int l = tid & 63, w = tid >> 6;
    const int wm = w >> 1, wn = w & 1;
    const int srow = l >> 2, sj = l & 3;       // staging: lane -> (row, chunk-slot)
    const int q = l >> 4, c16 = l & 15;        // MFMA lane coords

    floatx4 acc[4][4] = {};

    for (int k0 = 0; k0 < K; k0 += 32) {
        if (k0) __syncthreads();
#pragma unroll
        for (int i = 0; i < 2; i++) {
            int rb = (w * 2 + i) * 16;
            int r = rb + srow;
            int cc = sj ^ swz(r);
            gload_lds16(A + (size_t)(m0 + r) * K + k0 + cc * 8, Asm + rb * 32);
            gload_lds16(Bt + (size_t)(n0 + r) * K + k0 + cc * 8, Bsm + rb * 32);
        }
        __syncthreads();

        half8 af[4], bf[4];
#pragma unroll
        for (int t = 0; t < 4; t++) {
            int rA = wm * 64 + t * 16 + c16;
            af[t] = *(const half8*)&Asm[rA * 32 + ((q ^ swz(rA)) << 3)];
            int rB = wn * 64 + t * 16 + c16;
            bf[t] = *(const half8*)&Bsm[rB * 32 + ((q ^ swz(rB)) << 3)];
        }
#pragma unroll
        for (int mi = 0; mi < 4; mi++)
#pragma unroll
            for (int ni = 0; ni < 4; ni++)
                acc[mi][ni] = __builtin_amdgcn_mfma_f32_16x16x32_f16(
                    af[mi], bf[ni], acc[mi][ni], 0, 0, 0);
    }

    // Epilogue. C/D layout per 16x16 tile: col = c16, row = q*4 + reg.
    if (OUT16) {
        float bcol[4];
        float brow[4][4];
        if (!ROWBIAS) {
#pragma unroll
            for (int ni = 0; ni < 4; ni++)
                bcol[ni] = bias[n0 + wn * 64 + ni * 16 + c16];
        } else {
#pragma unroll
            for (int mi = 0; mi < 4; mi++) {
                float4 b4 = *(const float4*)&bias[m0 + wm * 64 + mi * 16 + q * 4];
                brow[mi][0] = b4.x; brow[mi][1] = b4.y;
                brow[mi][2] = b4.z; brow[mi][3] = b4.w;
            }
        }
        _Float16* C = (_Float16*)Cp;
#pragma unroll
        for (int ni = 0; ni < 4; ni++) {
            int col = n0 + wn * 64 + ni * 16 + c16;
#pragma unroll
            for (int mi = 0; mi < 4; mi++) {
                int row = m0 + wm * 64 + mi * 16 + q * 4;
#pragma unroll
                for (int r = 0; r < 4; r++) {
                    float b = ROWBIAS ? brow[mi][r] : bcol[ni];
                    C[(size_t)(row + r) * N + col] = (_Float16)(acc[mi][ni][r] + b);
                }
            }
        }
    } else {
        float* C = (float*)Cp;
#pragma unroll
        for (int ni = 0; ni < 4; ni++) {
            int col = n0 + wn * 64 + ni * 16 + c16;
#pragma unroll
            for (int mi = 0; mi < 4; mi++) {
                int row = m0 + wm * 64 + mi * 16 + q * 4;
#pragma unroll
                for (int r = 0; r < 4; r++)
                    C[(size_t)(row + r) * N + col] = acc[mi][ni][r];
            }
        }
    }
}

// ---------------------------------------------------------------------------
// qkv_gemm: ONE kernel, 768 blocks (3/CU), demuxed on RAW bid with a
// bijective XCD swizzle on the tile coords inside each segment.
// ---------------------------------------------------------------------------
__global__ __launch_bounds__(256, 3) void qkv_gemm(
    const _Float16* __restrict__ audio_h, const _Float16* __restrict__ text_h,
    const _Float16* __restrict__ Wq_t, const _Float16* __restrict__ Wk_t,
    const _Float16* __restrict__ Wv_t,
    const float* __restrict__ bq, const float* __restrict__ bk,
    const float* __restrict__ bv,
    _Float16* __restrict__ Qh, _Float16* __restrict__ Kh,
    _Float16* __restrict__ Vt)
{
    __shared__ __align__(16) _Float16 Asm[128 * 32];
    __shared__ __align__(16) _Float16 Bsm[128 * 32];
    const int bid = blockIdx.x;
    if (bid < 512) {
        int t = (bid & 7) * 64 + (bid >> 3);
        gemm_body<true, false>(audio_h, Wq_t, bq, Qh, 512, 512,
                               (t >> 2) * 128, (t & 3) * 128, Asm, Bsm);
    } else if (bid < 640) {
        int s = bid - 512;
        int t = (s & 7) * 16 + (s >> 3);
        gemm_body<true, false>(text_h, Wk_t, bk, Kh, 512, 768,
                               (t >> 2) * 128, (t & 3) * 128, Asm, Bsm);
    } else {
        int s = bid - 640;
        int t = (s & 7) * 16 + (s >> 3);   // XCD c -> batch z == c
        int z = t >> 4, by = (t >> 2) & 3, bx = t & 3;
        gemm_body<true, true>(Wv_t, text_h + (size_t)z * 393216, bv,
                              Vt + (size_t)z * 262144, 512, 768,
                              by * 128, bx * 128, Asm, Bsm);
    }
}

// ---------------------------------------------------------------------------
// attn: fused scores+softmax+PV, BARRIER-FREE hot loops.
//
// Key structural fact: wave w computes score/out cols [w*128,(w+1)*128),
// which need ONLY K/V rows in that band — the same rows wave w stages.
// K/V staging therefore has NO cross-wave dependency, so the QK^T and PV
// loops need no __syncthreads() at all. Each wave runs a private
// counted-vmcnt ping-pong pipeline (stage next 4KB half-band while
// computing current one, s_waitcnt vmcnt(4) between — never drains to 0
// inside the loop). Barriers in the whole kernel: 4 (Q-stage, 2x softmax
// reduce, P-publish).
//
//   LDS: QPs 32KB (Q, overwritten by P after softmax) + Ks 32KB (K, then V;
//   4 per-wave quarters) + red ~1KB = 65.5KB -> 2 blocks/CU.
// ---------------------------------------------------------------------------

// Stage half-band H (rows [w*128+H*64, +64), 32-col slice at K0) of SRC
// into this wave's quarter of Ks. 4 x 1KB issues.
#define STAGE_HALF(SRC, K0, H)                                              \
    do {                                                                    \
        _Pragma("unroll")                                                   \
        for (int i_ = 0; i_ < 4; i_++) {                                    \
            int rb_ = (w * 8 + (H) * 4 + i_) * 16;                          \
            int r_ = rb_ + srow;                                            \
            int cc_ = sj ^ swz(r_);                                         \
            gload_lds16((SRC) + (size_t)r_ * HIDDEN + (K0) + cc_ * 8,       \
                        &Ks[rb_ * 32]);                                     \
        }                                                                   \
    } while (0)

__global__ __launch_bounds__(256, 2) void attn(
    const _Float16* __restrict__ Qh, const _Float16* __restrict__ Kh,
    const _Float16* __restrict__ Vt, const int* __restrict__ mask,
    float* __restrict__ out)
{
    __shared__ __align__(16) _Float16 QPs[32 * 512];  // 32 KB: Q, then P
    __shared__ __align__(16) _Float16 Ks[512 * 32];   // 32 KB: K, then V
    __shared__ float red[4][32];
    __shared__ float red2[4][32];
    const int tid = threadIdx.x, l = tid & 63, w = tid >> 6;
    const int lin = blockIdx.x;
    const int tb = (lin & 7) * 64 + (lin >> 3);       // XCD c -> batch b == c
    const int b = tb >> 6, a0 = (tb & 63) * 32;
    const _Float16* Qb = Qh + (size_t)(b * ALEN + a0) * HIDDEN;
    const _Float16* Kb = Kh + (size_t)b * TLEN * HIDDEN;
    const _Float16* Vb = Vt + (size_t)b * TLEN * HIDDEN;  // [h][t]
    const int srow = l >> 2, sj = l & 3;
    const int q = l >> 4, c16 = l & 15;

    // ---- stage FULL Q once: wave w stages rows [w*8, w*8+8).
    // LDS chunk slot s of row r holds global chunk s ^ (r&7)  (chunk=16B).
#pragma unroll
    for (int i = 0; i < 8; i++) {
        int r = w * 8 + i;
        gload_lds16(Qb + (size_t)r * 512 + ((l ^ (r & 7)) << 3), &QPs[r * 512]);
    }
    __syncthreads();   // drains vmcnt(0): counted waits below start from 0

    // ---------------- QK^T: barrier-free pipelined ----------------
    floatx4 acc[2][8] = {};
    STAGE_HALF(Kb, 0, 0);          // outstanding: 4
    STAGE_HALF(Kb, 0, 1);          // outstanding: 8
#pragma unroll
    for (int ks = 0; ks < 16; ks++) {
        const int k0 = ks * 32;
        half8 af[2];
#pragma unroll
        for (int t = 0; t < 2; t++) {
            int rA = t * 16 + c16;
            af[t] = *(const half8*)&QPs[rA * 512 + ((((k0 >> 3) + q) ^ (rA & 7)) << 3)];
        }
#pragma unroll
        for (int h = 0; h < 2; h++) {
            // wait for this half's 4 loads (4 newer stay in flight),
            // except the very last half which drains to 0.
            if (ks == 15 && h == 1) { VMCNT(0); } else { VMCNT(4); }
            half8 bf[4];
#pragma unroll
            for (int t = 0; t < 4; t++) {
                int rB = w * 128 + h * 64 + t * 16 + c16;
                bf[t] = *(const half8*)&Ks[rB * 32 + ((q ^ swz(rB)) << 3)];
            }
#pragma unroll
            for (int mi = 0; mi < 2; mi++)
#pragma unroll
                for (int t = 0; t < 4; t++)
                    acc[mi][h * 4 + t] = __builtin_amdgcn_mfma_f32_16x16x32_f16(
                        af[mi], bf[t], acc[mi][h * 4 + t], 0, 0, 0);
            if (ks < 15) {
                LDS_REUSE_FENCE();            // bf reads done before overwrite
                STAGE_HALF(Kb, k0 + 32, h);   // back to 8 outstanding
            }
        }
    }

    // ---------------- mask + softmax ----------------
    const float scale = 0.044194173824159216f;   // 512^-0.5
    int mv[8];
#pragma unroll
    for (int ni = 0; ni < 8; ni++)
        mv[ni] = mask[b * TLEN + w * 128 + ni * 16 + c16];
#pragma unroll
    for (int mi = 0; mi < 2; mi++)
#pragma unroll
        for (int ni = 0; ni < 8; ni++)
#pragma unroll
            for (int r = 0; r < 4; r++)
                acc[mi][ni][r] = mv[ni] ? acc[mi][ni][r] * scale : -1e30f;

    // row max: in-lane over 8 n-tiles, shuffle over 16 col-lanes, LDS over waves
    float mx[2][4];
#pragma unroll
    for (int mi = 0; mi < 2; mi++)
#pragma unroll
        for (int r = 0; r < 4; r++) {
            float m = -1e30f;
#pragma unroll
            for (int ni = 0; ni < 8; ni++) m = fmaxf(m, acc[mi][ni][r]);
#pragma unroll
            for (int off = 1; off <= 8; off <<= 1) m = fmaxf(m, __shfl_xor(m, off));
            mx[mi][r] = m;
        }
    if (c16 == 0)
#pragma unroll
        for (int mi = 0; mi < 2; mi++)
#pragma unroll
            for (int r = 0; r < 4; r++) red[w][mi * 16 + q * 4 + r] = mx[mi][r];
    __syncthreads();
#pragma unroll
    for (int mi = 0; mi < 2; mi++)
#pragma unroll
        for (int r = 0; r < 4; r++) {
            int row = mi * 16 + q * 4 + r;
            mx[mi][r] = fmaxf(fmaxf(red[0][row], red[1][row]),
                              fmaxf(red[2][row], red[3][row]));
        }

    // exp + row sum
    float sm[2][4];
#pragma unroll
    for (int mi = 0; mi < 2; mi++)
#pragma unroll
        for (int r = 0; r < 4; r++) {
            float s = 0.f;
#pragma unroll
            for (int ni = 0; ni < 8; ni++) {
                float e = __expf(acc[mi][ni][r] - mx[mi][r]);
                acc[mi][ni][r] = e;
                s += e;
            }
#pragma unroll
            for (int off = 1; off <= 8; off <<= 1) s += __shfl_xor(s, off);
            sm[mi][r] = s;
        }
    if (c16 == 0)
#pragma unroll
        for (int mi = 0; mi < 2; mi++)
#pragma unroll
            for (int r = 0; r < 4; r++) red2[w][mi * 16 + q * 4 + r] = sm[mi][r];
    __syncthreads();

    // ---------------- P -> LDS (overwrites Q; all Q reads done) ----------
    // Element (row,col) at chunk slot (col>>3) ^ (row&7), offset col&7.
    _Float16* Ps = QPs;
#pragma unroll
    for (int mi = 0; mi < 2; mi++)
#pragma unroll
        for (int r = 0; r < 4; r++) {
            int row = mi * 16 + q * 4 + r;
            float inv = 1.f / (red2[0][row] + red2[1][row] + red2[2][row] + red2[3][row]);
#pragma unroll
            for (int ni = 0; ni < 8; ni++) {
                int col = w * 128 + ni * 16 + c16;
                Ps[row * 512 + ((((col >> 3) ^ (row & 7)) << 3) + (col & 7))] =
                    (_Float16)(acc[mi][ni][r] * inv);
            }
        }
    __syncthreads();   // publish P (cross-wave read in PV)

    // ---------------- PV: barrier-free pipelined ----------------
    // out[a][h] = sum_t P[a][t] * Vt[h][t]; V into own Ks quarter.
    floatx4 oacc[2][8] = {};
    STAGE_HALF(Vb, 0, 0);
    STAGE_HALF(Vb, 0, 1);
#pragma unroll
    for (int ts = 0; ts < 16; ts++) {
        const int t0 = ts * 32;
        half8 af[2];
#pragma unroll
        for (int t = 0; t < 2; t++) {
            int rA = t * 16 + c16;
            af[t] = *(const half8*)&Ps[rA * 512 + ((((t0 >> 3) + q) ^ (rA & 7)) << 3)];
        }
#pragma unroll
        for (int h = 0; h < 2; h++) {
            if (ts == 15 && h == 1) { VMCNT(0); } else { VMCNT(4); }
            half8 bf[4];
#pragma unroll
            for (int t = 0; t < 4; t++) {
                int rB = w * 128 + h * 64 + t * 16 + c16;
                bf[t] = *(const half8*)&Ks[rB * 32 + ((q ^ swz(rB)) << 3)];
            }
#pragma unroll
            for (int mi = 0; mi < 2; mi++)
#pragma unroll
                for (int t = 0; t < 4; t++)
                    oacc[mi][h * 4 + t] = __builtin_amdgcn_mfma_f32_16x16x32_f16(
                        af[mi], bf[t], oacc[mi][h * 4 + t], 0, 0, 0);
            if (ts < 15) {
                LDS_REUSE_FENCE();
                STAGE_HALF(Vb, t0 + 32, h);
            }
        }
    }

    // ---------------- epilogue: fp32 out ----------------
    float* Ob = out + (size_t)(b * ALEN + a0) * HIDDEN;
#pragma unroll
    for (int ni = 0; ni < 8; ni++) {
        int col = w * 128 + ni * 16 + c16;
#pragma unroll
        for (int mi = 0; mi < 2; mi++) {
            int row = mi * 16 + q * 4;
#pragma unroll
            for (int r = 0; r < 4; r++)
                Ob[(size_t)(row + r) * HIDDEN + col] = oacc[mi][ni][r];
        }
    }
}

// ---------------------------------------------------------------------------
extern "C" void kernel_launch(void* const* d_in, const int* in_sizes, int n_in,
                              void* d_out, int out_size, void* d_ws, size_t ws_size,
                              hipStream_t stream)
{
    const float* audio = (const float*)d_in[0];   // [8,2048,512]
    const float* text  = (const float*)d_in[1];   // [8,512,768]
    const float* Wq    = (const float*)d_in[2];   // [512,512]
    const float* bq    = (const float*)d_in[3];
    const float* Wk    = (const float*)d_in[4];   // [768,512]
    const float* bk    = (const float*)d_in[5];
    const float* Wv    = (const float*)d_in[6];   // [768,512]
    const float* bv    = (const float*)d_in[7];
    const int*   maskp = (const int*)d_in[8];     // [8,512]
    float* out = (float*)d_out;

    // d_out doubles as f16 scratch until attn overwrites it:
    //   [0 .. 8.39M) halfs: audio_h ; [8.39M .. 16.78M): Qh (= 33.5 MB exactly)
    _Float16* audio_h = (_Float16*)d_out;
    _Float16* Qh      = audio_h + (size_t)8388608;

    // ws layout (halfs)
    _Float16* ws16   = (_Float16*)d_ws;
    _Float16* text_h = ws16;                        // 3,145,728  [B*512][768]
    _Float16* Wq_t   = text_h + 3145728;            //   262,144  [512][512]
    _Float16* Wk_t   = Wq_t + 262144;               //   393,216  [512][768]
    _Float16* Wv_t   = Wk_t + 393216;               //   393,216  [512][768]
    _Float16* Kh     = Wv_t + 393216;               // 2,097,152  [B,512,512]
    _Float16* Vt     = Kh + 2097152;                // 2,097,152  [B,512(h),512(t)]

    // 1) all input conditioning in one dispatch
    prep<<<12288, 256, 0, stream>>>(audio, text, Wq, Wk, Wv,
                                    audio_h, text_h, Wq_t, Wk_t, Wv_t);
    // 2) Q + K + V^T GEMMs in one dispatch
    qkv_gemm<<<768, 256, 0, stream>>>(audio_h, text_h, Wq_t, Wk_t, Wv_t,
                                      bq, bk, bv, Qh, Kh, Vt);
    // 3) fused scores + softmax + PV; 512 blocks = 2/CU, batch-per-XCD
    attn<<<512, 256, 0, stream>>>(Qh, Kh, Vt, maskp, out);
}

// Round 5
// 165.244 us; speedup vs baseline: 1.0694x; 1.0694x over previous
//
#include <hip/hip_runtime.h>
#include <cstdint>
#include <cstddef>

#define AUDIO_DIM 512
#define TEXT_DIM  768
#define HIDDEN    512
#define BATCH     8
#define ALEN      2048
#define TLEN      512

typedef _Float16 half8 __attribute__((ext_vector_type(8)));
typedef _Float16 half4_t __attribute__((ext_vector_type(4)));
typedef float floatx4 __attribute__((ext_vector_type(4)));

#define AS1 __attribute__((address_space(1)))
#define AS3 __attribute__((address_space(3)))

// Async global->LDS, 16B per lane. LDS dest = wave-uniform base + lane*16.
__device__ __forceinline__ void gload_lds16(const void* g, void* l) {
    __builtin_amdgcn_global_load_lds((const AS1 void*)g, (AS3 void*)l, 16, 0, 0);
}

// XOR swizzle: 16B chunk c of row r lives at slot c ^ swz(r); makes the
// 64B-row fragment reads 2-way bank aliasing (free) instead of 8-way.
__device__ __forceinline__ int swz(int r) { return (r >> 1) & 3; }

// Counted vmcnt waits (T4, m135-verified semantics: wait until outstanding<=N).
#define VMCNT(N) asm volatile("s_waitcnt vmcnt(" #N ")" ::: "memory")

// ---------------------------------------------------------------------------
// prep: ONE kernel for all input conditioning.
// ---------------------------------------------------------------------------
__global__ __launch_bounds__(256) void prep(
    const float* __restrict__ audio, const float* __restrict__ text,
    const float* __restrict__ Wq, const float* __restrict__ Wk,
    const float* __restrict__ Wv,
    _Float16* __restrict__ audio_h, _Float16* __restrict__ text_h,
    _Float16* __restrict__ Wq_t, _Float16* __restrict__ Wk_t,
    _Float16* __restrict__ Wv_t)
{
    __shared__ _Float16 tt[32 * 33];
    const int bid = blockIdx.x, tid = threadIdx.x;
    if (bid < 11264) {
        const float* src; _Float16* dst; int i;
        if (bid < 8192) { src = audio; dst = audio_h; i = bid * 256 + tid; }
        else            { src = text;  dst = text_h;  i = (bid - 8192) * 256 + tid; }
        float4 v = ((const float4*)src)[i];
        half4_t h;
        h.x = (_Float16)v.x; h.y = (_Float16)v.y; h.z = (_Float16)v.z; h.w = (_Float16)v.w;
        ((half4_t*)dst)[i] = h;
    } else {
        const float* src; _Float16* dst; int R, lb;
        if (bid < 11520)      { lb = bid - 11264; src = Wq; dst = Wq_t; R = 512; }
        else if (bid < 11904) { lb = bid - 11520; src = Wk; dst = Wk_t; R = 768; }
        else                  { lb = bid - 11904; src = Wv; dst = Wv_t; R = 768; }
        const int C = 512;
        const int c0 = (lb & 15) * 32, r0 = (lb >> 4) * 32;
        const int tx = tid & 31, ty = tid >> 5;   // 32 x 8
#pragma unroll
        for (int i = 0; i < 4; i++) {
            int r = ty + i * 8;
            tt[r * 33 + tx] = (_Float16)src[(size_t)(r0 + r) * C + c0 + tx];
        }
        __syncthreads();
#pragma unroll
        for (int i = 0; i < 4; i++) {
            int r = ty + i * 8;
            dst[(size_t)(c0 + r) * R + r0 + tx] = tt[tx * 33 + r];
        }
    }
}

// ---------------------------------------------------------------------------
// Shared f16 MFMA GEMM body (unchanged): 128x128 tile, BK=32, 4 waves.
// ---------------------------------------------------------------------------
template <bool OUT16, bool ROWBIAS>
__device__ __forceinline__ void gemm_body(
    const _Float16* __restrict__ A, const _Float16* __restrict__ Bt,
    const float* __restrict__ bias, void* __restrict__ Cp,
    int N, int K, int m0, int n0, _Float16* Asm, _Float16* Bsm)
{
    const int tid = threadIdx.x;
    const int l = tid & 63, w = tid >> 6;
    const int wm = w >> 1, wn = w & 1;
    const int srow = l >> 2, sj = l & 3;
    const int q = l >> 4, c16 = l & 15;

    floatx4 acc[4][4] = {};

    for (int k0 = 0; k0 < K; k0 += 32) {
        if (k0) __syncthreads();
#pragma unroll
        for (int i = 0; i < 2; i++) {
            int rb = (w * 2 + i) * 16;
            int r = rb + srow;
            int cc = sj ^ swz(r);
            gload_lds16(A + (size_t)(m0 + r) * K + k0 + cc * 8, Asm + rb * 32);
            gload_lds16(Bt + (size_t)(n0 + r) * K + k0 + cc * 8, Bsm + rb * 32);
        }
        __syncthreads();

        half8 af[4], bf[4];
#pragma unroll
        for (int t = 0; t < 4; t++) {
            int rA = wm * 64 + t * 16 + c16;
            af[t] = *(const half8*)&Asm[rA * 32 + ((q ^ swz(rA)) << 3)];
            int rB = wn * 64 + t * 16 + c16;
            bf[t] = *(const half8*)&Bsm[rB * 32 + ((q ^ swz(rB)) << 3)];
        }
#pragma unroll
        for (int mi = 0; mi < 4; mi++)
#pragma unroll
            for (int ni = 0; ni < 4; ni++)
                acc[mi][ni] = __builtin_amdgcn_mfma_f32_16x16x32_f16(
                    af[mi], bf[ni], acc[mi][ni], 0, 0, 0);
    }

    if (OUT16) {
        float bcol[4];
        float brow[4][4];
        if (!ROWBIAS) {
#pragma unroll
            for (int ni = 0; ni < 4; ni++)
                bcol[ni] = bias[n0 + wn * 64 + ni * 16 + c16];
        } else {
#pragma unroll
            for (int mi = 0; mi < 4; mi++) {
                float4 b4 = *(const float4*)&bias[m0 + wm * 64 + mi * 16 + q * 4];
                brow[mi][0] = b4.x; brow[mi][1] = b4.y;
                brow[mi][2] = b4.z; brow[mi][3] = b4.w;
            }
        }
        _Float16* C = (_Float16*)Cp;
#pragma unroll
        for (int ni = 0; ni < 4; ni++) {
            int col = n0 + wn * 64 + ni * 16 + c16;
#pragma unroll
            for (int mi = 0; mi < 4; mi++) {
                int row = m0 + wm * 64 + mi * 16 + q * 4;
#pragma unroll
                for (int r = 0; r < 4; r++) {
                    float b = ROWBIAS ? brow[mi][r] : bcol[ni];
                    C[(size_t)(row + r) * N + col] = (_Float16)(acc[mi][ni][r] + b);
                }
            }
        }
    } else {
        float* C = (float*)Cp;
#pragma unroll
        for (int ni = 0; ni < 4; ni++) {
            int col = n0 + wn * 64 + ni * 16 + c16;
#pragma unroll
            for (int mi = 0; mi < 4; mi++) {
                int row = m0 + wm * 64 + mi * 16 + q * 4;
#pragma unroll
                for (int r = 0; r < 4; r++)
                    C[(size_t)(row + r) * N + col] = acc[mi][ni][r];
            }
        }
    }
}

// ---------------------------------------------------------------------------
// qkv_gemm (unchanged): 768 blocks, XCD-swizzled tile coords per segment.
// ---------------------------------------------------------------------------
__global__ __launch_bounds__(256, 3) void qkv_gemm(
    const _Float16* __restrict__ audio_h, const _Float16* __restrict__ text_h,
    const _Float16* __restrict__ Wq_t, const _Float16* __restrict__ Wk_t,
    const _Float16* __restrict__ Wv_t,
    const float* __restrict__ bq, const float* __restrict__ bk,
    const float* __restrict__ bv,
    _Float16* __restrict__ Qh, _Float16* __restrict__ Kh,
    _Float16* __restrict__ Vt)
{
    __shared__ __align__(16) _Float16 Asm[128 * 32];
    __shared__ __align__(16) _Float16 Bsm[128 * 32];
    const int bid = blockIdx.x;
    if (bid < 512) {
        int t = (bid & 7) * 64 + (bid >> 3);
        gemm_body<true, false>(audio_h, Wq_t, bq, Qh, 512, 512,
                               (t >> 2) * 128, (t & 3) * 128, Asm, Bsm);
    } else if (bid < 640) {
        int s = bid - 512;
        int t = (s & 7) * 16 + (s >> 3);
        gemm_body<true, false>(text_h, Wk_t, bk, Kh, 512, 768,
                               (t >> 2) * 128, (t & 3) * 128, Asm, Bsm);
    } else {
        int s = bid - 640;
        int t = (s & 7) * 16 + (s >> 3);   // XCD c -> batch z == c
        int z = t >> 4, by = (t >> 2) & 3, bx = t & 3;
        gemm_body<true, true>(Wv_t, text_h + (size_t)z * 393216, bv,
                              Vt + (size_t)z * 262144, 512, 768,
                              by * 128, bx * 128, Asm, Bsm);
    }
}

// ---------------------------------------------------------------------------
// attn v3: 64 Q-rows/block, 8 waves (512 thr), 256 blocks = 1 block/CU.
//
// vs R4 (32 rows, 4 waves, 512 blocks): halves block-aggregate K/V L2
// traffic (256 MB vs 512 MB), halves stage-issues per MFMA, and replaces
// the shallow half-band ping-pong with a true per-wave DOUBLE BUFFER:
// stage step s+2 right after computing step s -> one full k-step (~450 cyc
// /SIMD) of prefetch lead, covering L2 latency. Wave w owns cols
// [w*64,(w+1)*64) == its private 64 K-rows / 64 V-rows: the k/t loops have
// NO cross-wave dependency -> no barriers, counted vmcnt(4) only.
// No lgkm fence needed on buffer reuse: the MFMAs consuming the ds_reads
// force their retirement (compiler auto-waitcnt) before the next stage
// issues in program order.
// V prologue is issued BEFORE softmax so its latency hides under the
// reduction phase. 4 barriers total (Q publish, 2x reduce, P publish).
// LDS: Q/P 64KB + K/V 8w x 2buf x 4KB = 64KB + red 4KB = 132 KB.
//
// NOTE d_out aliasing: attn reads Qh (upper half of d_out) only in the
// initial Q-stage; writes land in the epilogue. All 256 blocks are
// co-resident (1/CU), so every block's Q-stage completes long before any
// block reaches its epilogue (same argument as R1-R4, which passed).
// ---------------------------------------------------------------------------

// Stage this wave's private 64-row band, 32-col slice at K0, into BUF.
// 4 x 1KB issues; LDS slot sj of row lr holds global chunk sj ^ swz(lr).
#define STAGE64(SRC, K0, BUF)                                               \
    do {                                                                    \
        _Pragma("unroll")                                                   \
        for (int i_ = 0; i_ < 4; i_++) {                                    \
            int lr_ = i_ * 16 + srow;                                       \
            int cc_ = sj ^ swz(lr_);                                        \
            gload_lds16((SRC) + (size_t)(w * 64 + lr_) * HIDDEN + (K0) + cc_ * 8, \
                        &(BUF)[i_ * 512]);                                  \
        }                                                                   \
    } while (0)

__global__ __launch_bounds__(512, 2) void attn(
    const _Float16* __restrict__ Qh, const _Float16* __restrict__ Kh,
    const _Float16* __restrict__ Vt, const int* __restrict__ mask,
    float* __restrict__ out)
{
    __shared__ __align__(16) _Float16 QPs[64 * 512];      // 64 KB: Q, then P
    __shared__ __align__(16) _Float16 Ks[8][2][64 * 32];  // 64 KB: K, then V
    __shared__ float red[8][64];
    __shared__ float red2[8][64];
    const int tid = threadIdx.x, l = tid & 63, w = tid >> 6;   // w in 0..7
    const int lin = blockIdx.x;
    const int tb = (lin & 7) * 32 + (lin >> 3);   // XCD c -> batch b == c
    const int b = tb >> 5, a0 = (tb & 31) * 64;
    const _Float16* Qb = Qh + (size_t)(b * ALEN + a0) * HIDDEN;
    const _Float16* Kb = Kh + (size_t)b * TLEN * HIDDEN;
    const _Float16* Vb = Vt + (size_t)b * TLEN * HIDDEN;  // [h][t]
    const int srow = l >> 2, sj = l & 3;
    const int q = l >> 4, c16 = l & 15;

    // mask to regs up front (keeps loop vmcnt counts deterministic)
    int mv[4];
#pragma unroll
    for (int ni = 0; ni < 4; ni++)
        mv[ni] = mask[b * TLEN + w * 64 + ni * 16 + c16];

    // ---- stage Q (shared, once): wave w stages rows [w*8, w*8+8).
    // LDS chunk slot s of row r holds global chunk s ^ (r&7)  (chunk=16B).
#pragma unroll
    for (int i = 0; i < 8; i++) {
        int r = w * 8 + i;
        gload_lds16(Qb + (size_t)r * 512 + ((l ^ (r & 7)) << 3), &QPs[r * 512]);
    }
    // K prologue into private double buffer (drained by the barrier too)
    STAGE64(Kb, 0, Ks[w][0]);
    STAGE64(Kb, 32, Ks[w][1]);
    __syncthreads();   // publish Q; vmcnt drains to 0 here

    // ---------------- QK^T: barrier-free, double-buffered ----------------
    floatx4 acc[4][4] = {};
#pragma unroll
    for (int ks = 0; ks < 16; ks++) {
        const int k0 = ks * 32;
        if (ks == 15) { VMCNT(0); } else { VMCNT(4); }
        half8 af[4], bf[4];
        const _Float16* kb = &Ks[w][ks & 1][0];
#pragma unroll
        for (int t = 0; t < 4; t++) {
            int rA = t * 16 + c16;
            af[t] = *(const half8*)&QPs[rA * 512 + ((((k0 >> 3) + q) ^ (rA & 7)) << 3)];
            bf[t] = *(const half8*)&kb[rA * 32 + ((q ^ swz(rA)) << 3)];
        }
#pragma unroll
        for (int mi = 0; mi < 4; mi++)
#pragma unroll
            for (int ni = 0; ni < 4; ni++)
                acc[mi][ni] = __builtin_amdgcn_mfma_f32_16x16x32_f16(
                    af[mi], bf[ni], acc[mi][ni], 0, 0, 0);
        if (ks < 14) STAGE64(Kb, k0 + 64, Ks[w][ks & 1]);   // stage step ks+2
    }

    // V prologue NOW: latency hides under softmax (barrier drains it there)
    STAGE64(Vb, 0, Ks[w][0]);
    STAGE64(Vb, 32, Ks[w][1]);

    // ---------------- mask + softmax ----------------
    const float scale = 0.044194173824159216f;   // 512^-0.5
#pragma unroll
    for (int mi = 0; mi < 4; mi++)
#pragma unroll
        for (int ni = 0; ni < 4; ni++)
#pragma unroll
            for (int r = 0; r < 4; r++)
                acc[mi][ni][r] = mv[ni] ? acc[mi][ni][r] * scale : -1e30f;

    float mx[4][4];
#pragma unroll
    for (int mi = 0; mi < 4; mi++)
#pragma unroll
        for (int r = 0; r < 4; r++) {
            float m = -1e30f;
#pragma unroll
            for (int ni = 0; ni < 4; ni++) m = fmaxf(m, acc[mi][ni][r]);
#pragma unroll
            for (int off = 1; off <= 8; off <<= 1) m = fmaxf(m, __shfl_xor(m, off));
            mx[mi][r] = m;
        }
    if (c16 == 0)
#pragma unroll
        for (int mi = 0; mi < 4; mi++)
#pragma unroll
            for (int r = 0; r < 4; r++) red[w][mi * 16 + q * 4 + r] = mx[mi][r];
    __syncthreads();
#pragma unroll
    for (int mi = 0; mi < 4; mi++)
#pragma unroll
        for (int r = 0; r < 4; r++) {
            int row = mi * 16 + q * 4 + r;
            float m = red[0][row];
#pragma unroll
            for (int ww = 1; ww < 8; ww++) m = fmaxf(m, red[ww][row]);
            mx[mi][r] = m;
        }

    float sm[4][4];
#pragma unroll
    for (int mi = 0; mi < 4; mi++)
#pragma unroll
        for (int r = 0; r < 4; r++) {
            float s = 0.f;
#pragma unroll
            for (int ni = 0; ni < 4; ni++) {
                float e = __expf(acc[mi][ni][r] - mx[mi][r]);
                acc[mi][ni][r] = e;
                s += e;
            }
#pragma unroll
            for (int off = 1; off <= 8; off <<= 1) s += __shfl_xor(s, off);
            sm[mi][r] = s;
        }
    if (c16 == 0)
#pragma unroll
        for (int mi = 0; mi < 4; mi++)
#pragma unroll
            for (int r = 0; r < 4; r++) red2[w][mi * 16 + q * 4 + r] = sm[mi][r];
    __syncthreads();

    // ---------------- P -> LDS (overwrites Q; all Q reads done) ----------
    // Element (row,col) at chunk slot (col>>3) ^ (row&7), offset col&7.
    _Float16* Ps = QPs;
#pragma unroll
    for (int mi = 0; mi < 4; mi++)
#pragma unroll
        for (int r = 0; r < 4; r++) {
            int row = mi * 16 + q * 4 + r;
            float s = red2[0][row];
#pragma unroll
            for (int ww = 1; ww < 8; ww++) s += red2[ww][row];
            float inv = 1.f / s;
#pragma unroll
            for (int ni = 0; ni < 4; ni++) {
                int col = w * 64 + ni * 16 + c16;
                Ps[row * 512 + ((((col >> 3) ^ (row & 7)) << 3) + (col & 7))] =
                    (_Float16)(acc[mi][ni][r] * inv);
            }
        }
    __syncthreads();   // publish P (cross-wave read in PV)

    // ---------------- PV: barrier-free, double-buffered ----------------
    // out[a][h] = sum_t P[a][t] * Vt[h][t]; V in own Ks half-buffers.
    floatx4 oacc[4][4] = {};
#pragma unroll
    for (int ts = 0; ts < 16; ts++) {
        const int t0 = ts * 32;
        if (ts == 15) { VMCNT(0); } else { VMCNT(4); }
        half8 af[4], bf[4];
        const _Float16* vb = &Ks[w][ts & 1][0];
#pragma unroll
        for (int t = 0; t < 4; t++) {
            int rA = t * 16 + c16;
            af[t] = *(const half8*)&Ps[rA * 512 + ((((t0 >> 3) + q) ^ (rA & 7)) << 3)];
            bf[t] = *(const half8*)&vb[rA * 32 + ((q ^ swz(rA)) << 3)];
        }
#pragma unroll
        for (int mi = 0; mi < 4; mi++)
#pragma unroll
            for (int ni = 0; ni < 4; ni++)
                oacc[mi][ni] = __builtin_amdgcn_mfma_f32_16x16x32_f16(
                    af[mi], bf[ni], oacc[mi][ni], 0, 0, 0);
        if (ts < 14) STAGE64(Vb, t0 + 64, Ks[w][ts & 1]);   // stage step ts+2
    }

    // ---------------- epilogue: fp32 out ----------------
    float* Ob = out + (size_t)(b * ALEN + a0) * HIDDEN;
#pragma unroll
    for (int ni = 0; ni < 4; ni++) {
        int col = w * 64 + ni * 16 + c16;
#pragma unroll
        for (int mi = 0; mi < 4; mi++) {
            int row = mi * 16 + q * 4;
#pragma unroll
            for (int r = 0; r < 4; r++)
                Ob[(size_t)(row + r) * HIDDEN + col] = oacc[mi][ni][r];
        }
    }
}

// ---------------------------------------------------------------------------
extern "C" void kernel_launch(void* const* d_in, const int* in_sizes, int n_in,
                              void* d_out, int out_size, void* d_ws, size_t ws_size,
                              hipStream_t stream)
{
    const float* audio = (const float*)d_in[0];   // [8,2048,512]
    const float* text  = (const float*)d_in[1];   // [8,512,768]
    const float* Wq    = (const float*)d_in[2];   // [512,512]
    const float* bq    = (const float*)d_in[3];
    const float* Wk    = (const float*)d_in[4];   // [768,512]
    const float* bk    = (const float*)d_in[5];
    const float* Wv    = (const float*)d_in[6];   // [768,512]
    const float* bv    = (const float*)d_in[7];
    const int*   maskp = (const int*)d_in[8];     // [8,512]
    float* out = (float*)d_out;

    // d_out doubles as f16 scratch until attn overwrites it:
    //   [0 .. 8.39M) halfs: audio_h ; [8.39M .. 16.78M): Qh (= 33.5 MB exactly)
    _Float16* audio_h = (_Float16*)d_out;
    _Float16* Qh      = audio_h + (size_t)8388608;

    // ws layout (halfs)
    _Float16* ws16   = (_Float16*)d_ws;
    _Float16* text_h = ws16;                        // 3,145,728  [B*512][768]
    _Float16* Wq_t   = text_h + 3145728;            //   262,144  [512][512]
    _Float16* Wk_t   = Wq_t + 262144;               //   393,216  [512][768]
    _Float16* Wv_t   = Wk_t + 393216;               //   393,216  [512][768]
    _Float16* Kh     = Wv_t + 393216;               // 2,097,152  [B,512,512]
    _Float16* Vt     = Kh + 2097152;                // 2,097,152  [B,512(h),512(t)]

    // 1) all input conditioning in one dispatch
    prep<<<12288, 256, 0, stream>>>(audio, text, Wq, Wk, Wv,
                                    audio_h, text_h, Wq_t, Wk_t, Wv_t);
    // 2) Q + K + V^T GEMMs in one dispatch
    qkv_gemm<<<768, 256, 0, stream>>>(audio_h, text_h, Wq_t, Wk_t, Wv_t,
                                      bq, bk, bv, Qh, Kh, Vt);
    // 3) fused scores+softmax+PV: 256 blocks x 512 thr, 1 block/CU,
    //    batch-per-XCD swizzle
    attn<<<256, 512, 0, stream>>>(Qh, Kh, Vt, maskp, out);
}